// Round 3
// baseline (1245.958 us; speedup 1.0000x reference)
//
#include <hip/hip_runtime.h>
#include <math.h>

// ---------------- problem constants ----------------
#define Bn 4
#define Tn 8
#define Hn 120
#define Wn 160
#define HWn (Hn * Wn)
#define NON_SEMn 4
#define CATn 16
#define MAP_CHn 20
#define FEAT_CHn 24
#define LOCAL_Mn 240
#define GLOBAL_Mn 960
#define M2n (LOCAL_Mn * LOCAL_Mn)
#define TBMn (Tn * Bn * M2n)                  // 1,843,200

#define DEG2RADf ((float)0.017453292519943295)

// output layout (float element offsets into d_out)
#define OUT_FEATS 0                           // B*T*24*M2 = 44,236,800
#define OUT_LMAP  44236800                    // B*20*M2   =  4,608,000
#define OUT_GMAP  48844800                    // B*20*960² = 73,728,000
#define OUT_LP    122572800                   // B*T*3
#define OUT_GP    122572896                   // B*T*3
#define OUT_BNDS  122572992                   // B*T*4 (written as float)
#define OUT_ORGS  122573120                   // B*T*3

// workspace layout (float element offsets into d_ws)
// scratch: exp[TBM] ++ obst[TBM] ++ sem[TBM][16]  (sem is CELL-major: one
// pixel's 16 channels = 16 consecutive floats = one 64B cache line)
#define WS_LPOSE   0                          // T*B*3 = 96
#define WS_ANYDONE 96                         // B (float 0/1), padded to 128
#define WS_SCR     128
#define SCR_FLOATS ((size_t)TBMn * 18)

// ---------------- kernels ----------------

// Poses/bounds/origins evolve independently of the maps: compute all T steps
// up front, write pose outputs, stash per-step lpose + any_done flag in ws.
__global__ void pose_kernel(const float* __restrict__ pose_delta,
                            const int* __restrict__ done_flags,
                            const int* __restrict__ upd_flags,
                            const float* __restrict__ init_lpose,
                            const float* __restrict__ init_gpose,
                            const int* __restrict__ init_bounds,
                            const float* __restrict__ init_origins,
                            float* __restrict__ ws_lpose,
                            float* __restrict__ ws_anydone,
                            float* __restrict__ out_lp,
                            float* __restrict__ out_gp,
                            float* __restrict__ out_bnds,
                            float* __restrict__ out_orgs) {
#pragma clang fp contract(off)
    int b = threadIdx.x;
    if (b >= Bn) return;
    float lx = init_lpose[b * 3 + 0], ly = init_lpose[b * 3 + 1], lz = init_lpose[b * 3 + 2];
    float gx = init_gpose[b * 3 + 0], gy = init_gpose[b * 3 + 1], gz = init_gpose[b * 3 + 2];
    int b0 = init_bounds[b * 4 + 0], b1 = init_bounds[b * 4 + 1];
    int b2i = init_bounds[b * 4 + 2], b3 = init_bounds[b * 4 + 3];
    float ox = init_origins[b * 3 + 0], oy = init_origins[b * 3 + 1], oz = init_origins[b * 3 + 2];
    float anyd = 0.0f;
    for (int t = 0; t < Tn; t++) {
        int done = done_flags[b * Tn + t];
        int upd  = upd_flags[b * Tn + t];
        if (done) {
            lx = 600.0f; ly = 600.0f; lz = 0.0f;
            gx = 2400.0f; gy = 2400.0f; gz = 0.0f;
            b0 = 360; b1 = 600; b2i = 360; b3 = 600;
            ox = 1800.0f; oy = 1800.0f; oz = 0.0f;
            anyd = 1.0f;
        }
        float th = lz * DEG2RADf;
        float c = cosf(th), s = sinf(th);
        float d0 = pose_delta[(b * Tn + t) * 3 + 0];
        float d1 = pose_delta[(b * Tn + t) * 3 + 1];
        float d2 = pose_delta[(b * Tn + t) * 3 + 2];
        lx = lx + (d0 * c - d1 * s);
        ly = ly + (d0 * s + d1 * c);
        lz = lz + d2;
        if (upd) { gx = lx + ox; gy = ly + oy; gz = lz + oz; }
        ws_lpose[(t * Bn + b) * 3 + 0] = lx;
        ws_lpose[(t * Bn + b) * 3 + 1] = ly;
        ws_lpose[(t * Bn + b) * 3 + 2] = lz;
        out_lp[(b * Tn + t) * 3 + 0] = lx;
        out_lp[(b * Tn + t) * 3 + 1] = ly;
        out_lp[(b * Tn + t) * 3 + 2] = lz;
        out_gp[(b * Tn + t) * 3 + 0] = gx;
        out_gp[(b * Tn + t) * 3 + 1] = gy;
        out_gp[(b * Tn + t) * 3 + 2] = gz;
        out_bnds[(b * Tn + t) * 4 + 0] = (float)b0;
        out_bnds[(b * Tn + t) * 4 + 1] = (float)b1;
        out_bnds[(b * Tn + t) * 4 + 2] = (float)b2i;
        out_bnds[(b * Tn + t) * 4 + 3] = (float)b3;
        out_orgs[(b * Tn + t) * 3 + 0] = ox;
        out_orgs[(b * Tn + t) * 3 + 1] = oy;
        out_orgs[(b * Tn + t) * 3 + 2] = oz;
    }
    ws_anydone[b] = anyd;
}

// All (t,b,pixel) in one launch: unproject, transform, splat into per-t scratch.
// exp/obst used downstream only as clip(count,0,1) -> plain stores of 1.0f.
// sem: 16 atomicAdds into 16 CONSECUTIVE floats (one cache line per pixel).
__global__ void project_kernel(const float* __restrict__ obs,
                               const float* __restrict__ cam,
                               const float* __restrict__ ws_lpose,
                               float* __restrict__ scr,
                               float fx) {
#pragma clang fp contract(off)
    int idx = blockIdx.x * blockDim.x + threadIdx.x;
    if (idx >= Tn * Bn * HWn) return;
    int p = idx % HWn;
    int tb = idx / HWn;
    int b = tb % Bn;
    int t = tb / Bn;
    int h = p / Wn, w = p % Wn;
    const float* ob = obs + (size_t)((b * Tn + t) * MAP_CHn) * HWn;
    float depth = ob[3 * HWn + p] * 400.0f + 50.0f;
    float u = (float)w - 80.0f;   // CX = W/2
    float v = 60.0f - (float)h;   // CY = H/2
    float px = u * depth / fx;
    float py = v * depth / fx;    // FY == FX
    float pz = depth;
    const float* Tm = cam + (size_t)(b * Tn + t) * 16;
    float X = ((Tm[0] * px + Tm[1] * py) + Tm[2] * pz) + Tm[3];
    float Y = ((Tm[4] * px + Tm[5] * py) + Tm[6] * pz) + Tm[7];
    float Z = ((Tm[8] * px + Tm[9] * py) + Tm[10] * pz) + Tm[11];
    float x_f = Z;
    float y_l = -X;
    float z_u = Y + 88.0f;        // CAM_H_CM
    float lx = ws_lpose[(t * Bn + b) * 3 + 0];
    float ly = ws_lpose[(t * Bn + b) * 3 + 1];
    float lz = ws_lpose[(t * Bn + b) * 3 + 2];
    float th2 = lz * DEG2RADf;
    float c2 = cosf(th2), s2 = sinf(th2);
    float wx = (lx + x_f * c2) - y_l * s2;
    float wy = (ly + x_f * s2) + y_l * c2;
    int ix = (int)floorf(wx / 5.0f);
    int iy = (int)floorf(wy / 5.0f);
    bool valid = (depth > 25.0f) && (depth < 500.0f) &&
                 (ix >= 0) && (ix < LOCAL_Mn) && (iy >= 0) && (iy < LOCAL_Mn);
    if (!valid) return;
    int base = (t * Bn + b) * M2n + iy * LOCAL_Mn + ix;   // [t][b][cell]
    scr[base] = 1.0f;                                     // exp hit
    if (z_u > 25.0f && z_u < 150.0f)
        scr[TBMn + base] = 1.0f;                          // obst hit
    float* sp = scr + 2 * (size_t)TBMn + (size_t)base * CATn;  // one 64B line
#pragma unroll
    for (int c = 0; c < CATn; c++) {
        float sv = ob[(size_t)(NON_SEMn + c) * HWn + p];
        atomicAdd(&sp[c], sv);
    }
}

// Per cell: carry lmap(20) + crop(20) in registers across all T steps.
// Reads exp/obst + one 64B sem line per step; writes 24 feat ch/step;
// final lmap + gmap window at the end.
__global__ void update_kernel(const float* __restrict__ scr,
                              const int* __restrict__ done_flags,
                              const int* __restrict__ upd_flags,
                              const float* __restrict__ ws_lpose,
                              const float* __restrict__ init_lmap,
                              const float* __restrict__ init_gmap,
                              const int* __restrict__ init_bounds,
                              float* __restrict__ out_feats,
                              float* __restrict__ out_lmap,
                              float* __restrict__ out_gmap) {
#pragma clang fp contract(off)
    int idx = blockIdx.x * blockDim.x + threadIdx.x;
    if (idx >= Bn * M2n) return;
    int b = idx / M2n, j = idx % M2n;
    int y = j / LOCAL_Mn, x = j % LOCAL_Mn;
    int y1 = init_bounds[b * 4 + 0];
    int x1 = init_bounds[b * 4 + 2];

    float lm[MAP_CHn], cr[MAP_CHn];
#pragma unroll
    for (int ch = 0; ch < MAP_CHn; ch++)
        lm[ch] = init_lmap[((size_t)(b * MAP_CHn + ch)) * M2n + j];
#pragma unroll
    for (int ch = 0; ch < MAP_CHn; ch++)
        cr[ch] = init_gmap[((size_t)(b * MAP_CHn + ch) * GLOBAL_Mn + (y1 + y)) * GLOBAL_Mn + (x1 + x)];

    for (int t = 0; t < Tn; t++) {
        int done = done_flags[b * Tn + t];
        int upd  = upd_flags[b * Tn + t];
        if (done) {
#pragma unroll
            for (int ch = 0; ch < MAP_CHn; ch++) { lm[ch] = 0.0f; cr[ch] = 0.0f; }
        }
        float lx = ws_lpose[(t * Bn + b) * 3 + 0];
        float ly = ws_lpose[(t * Bn + b) * 3 + 1];
        float dxg = (float)x - lx / 5.0f;
        float dyg = (float)y - ly / 5.0f;
        float d2 = dxg * dxg + dyg * dyg;
        float agent = (d2 <= 4.0f) ? 1.0f : 0.0f;
        float close = (d2 <= 9.0f) ? 1.0f : 0.0f;

        int base = (t * Bn + b) * M2n + j;
        float expv  = scr[base];
        float obstv = scr[TBMn + base];
        lm[0] = fmaxf(lm[0], fminf(fmaxf(obstv, 0.0f), 1.0f));
        lm[1] = fmaxf(lm[1], fminf(fmaxf(expv, 0.0f), 1.0f));
        lm[2] = agent;
        lm[3] = fmaxf(lm[3], close);
        const float4* semline = (const float4*)(scr + 2 * (size_t)TBMn + (size_t)base * CATn);
        float4 s0 = semline[0], s1 = semline[1], s2v = semline[2], s3 = semline[3];
        float sem[CATn] = { s0.x, s0.y, s0.z, s0.w, s1.x, s1.y, s1.z, s1.w,
                            s2v.x, s2v.y, s2v.z, s2v.w, s3.x, s3.y, s3.z, s3.w };
#pragma unroll
        for (int c = 0; c < CATn; c++)
            lm[NON_SEMn + c] = fmaxf(lm[NON_SEMn + c], fminf(fmaxf(sem[c], 0.0f), 1.0f));
        if (upd) {
#pragma unroll
            for (int ch = 0; ch < MAP_CHn; ch++) cr[ch] = fmaxf(cr[ch], lm[ch]);
        }

        size_t fb = ((size_t)(b * Tn + t) * FEAT_CHn) * M2n + j;
#pragma unroll
        for (int ch = 0; ch < NON_SEMn; ch++) out_feats[fb + (size_t)ch * M2n] = lm[ch];
#pragma unroll
        for (int ch = 0; ch < NON_SEMn; ch++) out_feats[fb + (size_t)(NON_SEMn + ch) * M2n] = cr[ch];
#pragma unroll
        for (int c = 0; c < CATn; c++) out_feats[fb + (size_t)(2 * NON_SEMn + c) * M2n] = lm[NON_SEMn + c];
    }

#pragma unroll
    for (int ch = 0; ch < MAP_CHn; ch++)
        out_lmap[((size_t)(b * MAP_CHn + ch)) * M2n + j] = lm[ch];
#pragma unroll
    for (int ch = 0; ch < MAP_CHn; ch++)
        out_gmap[((size_t)(b * MAP_CHn + ch) * GLOBAL_Mn + (y1 + y)) * GLOBAL_Mn + (x1 + x)] = cr[ch];
}

// Outside-window global map, float4-vectorized. Window cells are written by
// update_kernel; the fixed window [360,600) is 4-aligned so float4 never
// straddles its boundary. anydone -> write zeros without reading init_gmap.
__global__ void final_gmap_kernel(const float* __restrict__ init_gmap,
                                  const int* __restrict__ init_bounds,
                                  const float* __restrict__ anydone,
                                  float* __restrict__ out_gmap) {
    size_t i4 = (size_t)blockIdx.x * blockDim.x + threadIdx.x;
    const size_t total4 = (size_t)Bn * MAP_CHn * GLOBAL_Mn * GLOBAL_Mn / 4;
    if (i4 >= total4) return;
    size_t f = i4 * 4;
    int gx = (int)(f % GLOBAL_Mn);
    size_t r = f / GLOBAL_Mn;
    int gy = (int)(r % GLOBAL_Mn);
    size_t bc = r / GLOBAL_Mn;      // b*MAP_CH + ch
    int b = (int)(bc / MAP_CHn);
    int y1 = init_bounds[b * 4 + 0];
    int x1 = init_bounds[b * 4 + 2];
    if (gy >= y1 && gy < y1 + LOCAL_Mn && gx >= x1 && gx < x1 + LOCAL_Mn) return;
    float4 v;
    if (anydone[b] != 0.0f) {
        v = make_float4(0.0f, 0.0f, 0.0f, 0.0f);
    } else {
        v = *(const float4*)(init_gmap + f);
    }
    *(float4*)(out_gmap + f) = v;
}

// ---------------- launch ----------------
extern "C" void kernel_launch(void* const* d_in, const int* in_sizes, int n_in,
                              void* d_out, int out_size, void* d_ws, size_t ws_size,
                              hipStream_t stream) {
    const float* obs        = (const float*)d_in[0];
    const float* pose_delta = (const float*)d_in[1];
    const int*   done_flags = (const int*)d_in[2];
    const int*   upd_flags  = (const int*)d_in[3];
    const float* cam_poses  = (const float*)d_in[4];
    const float* init_lmap  = (const float*)d_in[5];
    const float* init_gmap  = (const float*)d_in[6];
    const float* init_lpose = (const float*)d_in[7];
    const float* init_gpose = (const float*)d_in[8];
    const int*   init_bnds  = (const int*)d_in[9];
    const float* init_orgs  = (const float*)d_in[10];

    float* out = (float*)d_out;
    float* ws  = (float*)d_ws;

    float* ws_lpose = ws + WS_LPOSE;
    float* ws_anyd  = ws + WS_ANYDONE;
    float* scr      = ws + WS_SCR;

    // FX = W / (2*tan(deg2rad(HFOV)/2)), double math then f32 (matches numpy)
    float fx = (float)(160.0 / (2.0 * tan(79.0 * M_PI / 180.0 / 2.0)));

    pose_kernel<<<1, 64, 0, stream>>>(pose_delta, done_flags, upd_flags,
                                      init_lpose, init_gpose, init_bnds, init_orgs,
                                      ws_lpose, ws_anyd,
                                      out + OUT_LP, out + OUT_GP,
                                      out + OUT_BNDS, out + OUT_ORGS);

    hipMemsetAsync(scr, 0, SCR_FLOATS * sizeof(float), stream);

    project_kernel<<<(Tn * Bn * HWn + 255) / 256, 256, 0, stream>>>(
        obs, cam_poses, ws_lpose, scr, fx);

    update_kernel<<<(Bn * M2n + 255) / 256, 256, 0, stream>>>(
        scr, done_flags, upd_flags, ws_lpose, init_lmap, init_gmap, init_bnds,
        out + OUT_FEATS, out + OUT_LMAP, out + OUT_GMAP);

    const size_t gmap_total4 = (size_t)Bn * MAP_CHn * GLOBAL_Mn * GLOBAL_Mn / 4;
    final_gmap_kernel<<<(int)((gmap_total4 + 255) / 256), 256, 0, stream>>>(
        init_gmap, init_bnds, ws_anyd, out + OUT_GMAP);
}

// Round 4
// 925.460 us; speedup vs baseline: 1.3463x; 1.3463x over previous
//
#include <hip/hip_runtime.h>
#include <math.h>

// ---------------- problem constants ----------------
#define Bn 4
#define Tn 8
#define Hn 120
#define Wn 160
#define HWn (Hn * Wn)
#define NON_SEMn 4
#define CATn 16
#define MAP_CHn 20
#define FEAT_CHn 24
#define LOCAL_Mn 240
#define GLOBAL_Mn 960
#define M2n (LOCAL_Mn * LOCAL_Mn)
#define TBMn (Tn * Bn * M2n)                  // 1,843,200 cells
#define Pn (Tn * Bn * HWn)                    // 614,400 pixels
#define NBLK_SCAN 1800                        // TBMn / 1024

#define DEG2RADf ((float)0.017453292519943295)

// output layout (float element offsets into d_out)
#define OUT_FEATS 0                           // B*T*24*M2 = 44,236,800
#define OUT_LMAP  44236800                    // B*20*M2   =  4,608,000
#define OUT_GMAP  48844800                    // B*20*960² = 73,728,000
#define OUT_LP    122572800                   // B*T*3
#define OUT_GP    122572896                   // B*T*3
#define OUT_BNDS  122572992                   // B*T*4 (written as float)
#define OUT_ORGS  122573120                   // B*T*3

// workspace layout (4-byte element offsets into d_ws)
#define WS_LPOSE  0                           // T*B*3 = 96
#define WS_ANYD   96                          // B, padded to 128
#define WS_EXP    128                         // TBM floats (0/1)
#define WS_OBST   (WS_EXP + TBMn)             // TBM floats (0/1)
#define WS_CNT    (WS_OBST + TBMn)            // TBM uint  (memset w/ exp/obst)
#define WS_OFF    (WS_CNT + TBMn)             // TBM uint  (exclusive scan)
#define WS_CUR    (WS_OFF + TBMn)             // TBM uint  (scatter cursors)
#define WS_BSUM   (WS_CUR + TBMn)             // 2048 uint
#define WS_CELL   (WS_BSUM + 2048)            // P int (cell id or -1)
#define WS_LIST   (WS_CELL + Pn)              // P uint (pixel ids, binned)
#define WS_REC    (WS_LIST + Pn)              // P*16 floats (sem records, 64B/pixel)

// ---------------- kernels ----------------

__global__ void pose_kernel(const float* __restrict__ pose_delta,
                            const int* __restrict__ done_flags,
                            const int* __restrict__ upd_flags,
                            const float* __restrict__ init_lpose,
                            const float* __restrict__ init_gpose,
                            const int* __restrict__ init_bounds,
                            const float* __restrict__ init_origins,
                            float* __restrict__ ws_lpose,
                            float* __restrict__ ws_anydone,
                            float* __restrict__ out_lp,
                            float* __restrict__ out_gp,
                            float* __restrict__ out_bnds,
                            float* __restrict__ out_orgs) {
#pragma clang fp contract(off)
    int b = threadIdx.x;
    if (b >= Bn) return;
    float lx = init_lpose[b * 3 + 0], ly = init_lpose[b * 3 + 1], lz = init_lpose[b * 3 + 2];
    float gx = init_gpose[b * 3 + 0], gy = init_gpose[b * 3 + 1], gz = init_gpose[b * 3 + 2];
    int b0 = init_bounds[b * 4 + 0], b1 = init_bounds[b * 4 + 1];
    int b2i = init_bounds[b * 4 + 2], b3 = init_bounds[b * 4 + 3];
    float ox = init_origins[b * 3 + 0], oy = init_origins[b * 3 + 1], oz = init_origins[b * 3 + 2];
    float anyd = 0.0f;
    for (int t = 0; t < Tn; t++) {
        int done = done_flags[b * Tn + t];
        int upd  = upd_flags[b * Tn + t];
        if (done) {
            lx = 600.0f; ly = 600.0f; lz = 0.0f;
            gx = 2400.0f; gy = 2400.0f; gz = 0.0f;
            b0 = 360; b1 = 600; b2i = 360; b3 = 600;
            ox = 1800.0f; oy = 1800.0f; oz = 0.0f;
            anyd = 1.0f;
        }
        float th = lz * DEG2RADf;
        float c = cosf(th), s = sinf(th);
        float d0 = pose_delta[(b * Tn + t) * 3 + 0];
        float d1 = pose_delta[(b * Tn + t) * 3 + 1];
        float d2 = pose_delta[(b * Tn + t) * 3 + 2];
        lx = lx + (d0 * c - d1 * s);
        ly = ly + (d0 * s + d1 * c);
        lz = lz + d2;
        if (upd) { gx = lx + ox; gy = ly + oy; gz = lz + oz; }
        ws_lpose[(t * Bn + b) * 3 + 0] = lx;
        ws_lpose[(t * Bn + b) * 3 + 1] = ly;
        ws_lpose[(t * Bn + b) * 3 + 2] = lz;
        out_lp[(b * Tn + t) * 3 + 0] = lx;
        out_lp[(b * Tn + t) * 3 + 1] = ly;
        out_lp[(b * Tn + t) * 3 + 2] = lz;
        out_gp[(b * Tn + t) * 3 + 0] = gx;
        out_gp[(b * Tn + t) * 3 + 1] = gy;
        out_gp[(b * Tn + t) * 3 + 2] = gz;
        out_bnds[(b * Tn + t) * 4 + 0] = (float)b0;
        out_bnds[(b * Tn + t) * 4 + 1] = (float)b1;
        out_bnds[(b * Tn + t) * 4 + 2] = (float)b2i;
        out_bnds[(b * Tn + t) * 4 + 3] = (float)b3;
        out_orgs[(b * Tn + t) * 3 + 0] = ox;
        out_orgs[(b * Tn + t) * 3 + 1] = oy;
        out_orgs[(b * Tn + t) * 3 + 2] = oz;
    }
    ws_anydone[b] = anyd;
}

// Per pixel: project, store exp/obst hit (plain stores of 1.0f), write 64B sem
// record (coalesced), cell id, and ONE int atomicAdd on the cell counter.
__global__ void project_bin_kernel(const float* __restrict__ obs,
                                   const float* __restrict__ cam,
                                   const float* __restrict__ ws_lpose,
                                   float* __restrict__ g_exp,
                                   float* __restrict__ g_obst,
                                   unsigned* __restrict__ cnt,
                                   int* __restrict__ cellid,
                                   float* __restrict__ rec,
                                   float fx) {
#pragma clang fp contract(off)
    int g = blockIdx.x * blockDim.x + threadIdx.x;
    if (g >= Pn) return;
    int p = g % HWn;
    int tb = g / HWn;
    int b = tb % Bn;
    int t = tb / Bn;
    int h = p / Wn, w = p % Wn;
    const float* ob = obs + (size_t)((b * Tn + t) * MAP_CHn) * HWn;
    float depth = ob[3 * HWn + p] * 400.0f + 50.0f;
    float u = (float)w - 80.0f;
    float v = 60.0f - (float)h;
    float px = u * depth / fx;
    float py = v * depth / fx;
    float pz = depth;
    const float* Tm = cam + (size_t)(b * Tn + t) * 16;
    float X = ((Tm[0] * px + Tm[1] * py) + Tm[2] * pz) + Tm[3];
    float Y = ((Tm[4] * px + Tm[5] * py) + Tm[6] * pz) + Tm[7];
    float Z = ((Tm[8] * px + Tm[9] * py) + Tm[10] * pz) + Tm[11];
    float x_f = Z;
    float y_l = -X;
    float z_u = Y + 88.0f;
    float lx = ws_lpose[(t * Bn + b) * 3 + 0];
    float ly = ws_lpose[(t * Bn + b) * 3 + 1];
    float lz = ws_lpose[(t * Bn + b) * 3 + 2];
    float th2 = lz * DEG2RADf;
    float c2 = cosf(th2), s2 = sinf(th2);
    float wx = (lx + x_f * c2) - y_l * s2;
    float wy = (ly + x_f * s2) + y_l * c2;
    int ix = (int)floorf(wx / 5.0f);
    int iy = (int)floorf(wy / 5.0f);
    bool valid = (depth > 25.0f) && (depth < 500.0f) &&
                 (ix >= 0) && (ix < LOCAL_Mn) && (iy >= 0) && (iy < LOCAL_Mn);

    // sem record: 16 coalesced channel reads -> one 64B record per pixel
    float4 r[4];
#pragma unroll
    for (int q = 0; q < 4; q++) {
        r[q].x = ob[(size_t)(NON_SEMn + 4 * q + 0) * HWn + p];
        r[q].y = ob[(size_t)(NON_SEMn + 4 * q + 1) * HWn + p];
        r[q].z = ob[(size_t)(NON_SEMn + 4 * q + 2) * HWn + p];
        r[q].w = ob[(size_t)(NON_SEMn + 4 * q + 3) * HWn + p];
    }
    float4* rp = (float4*)(rec + (size_t)g * CATn);
#pragma unroll
    for (int q = 0; q < 4; q++) rp[q] = r[q];

    int cell = -1;
    if (valid) {
        cell = (t * Bn + b) * M2n + iy * LOCAL_Mn + ix;
        g_exp[cell] = 1.0f;
        if (z_u > 25.0f && z_u < 150.0f) g_obst[cell] = 1.0f;
        atomicAdd(&cnt[cell], 1u);
    }
    cellid[g] = cell;
}

// Scan level 1: each block scans 1024 counts (256 thr x 4), writes local
// exclusive prefixes to off[] and the block total to bsum[].
__global__ void scan1_kernel(const unsigned* __restrict__ cnt,
                             unsigned* __restrict__ off,
                             unsigned* __restrict__ bsum) {
    __shared__ unsigned s[256];
    int tid = threadIdx.x;
    int base = blockIdx.x * 1024 + tid * 4;
    unsigned v0 = cnt[base], v1 = cnt[base + 1], v2 = cnt[base + 2], v3 = cnt[base + 3];
    unsigned tsum = v0 + v1 + v2 + v3;
    s[tid] = tsum;
    __syncthreads();
    for (int d = 1; d < 256; d <<= 1) {
        unsigned a = (tid >= d) ? s[tid - d] : 0u;
        __syncthreads();
        s[tid] += a;
        __syncthreads();
    }
    unsigned excl = s[tid] - tsum;
    if (tid == 255) bsum[blockIdx.x] = s[255];
    off[base]     = excl;
    off[base + 1] = excl + v0;
    off[base + 2] = excl + v0 + v1;
    off[base + 3] = excl + v0 + v1 + v2;
}

// Scan level 2: single block exclusive-scans bsum[NBLK_SCAN] in place.
__global__ void scan2_kernel(unsigned* __restrict__ bsum) {
    __shared__ unsigned s[256];
    int tid = threadIdx.x;
    unsigned run = 0;
    for (int base = 0; base < NBLK_SCAN; base += 256) {
        int i = base + tid;
        unsigned v = (i < NBLK_SCAN) ? bsum[i] : 0u;
        s[tid] = v;
        __syncthreads();
        for (int d = 1; d < 256; d <<= 1) {
            unsigned a = (tid >= d) ? s[tid - d] : 0u;
            __syncthreads();
            s[tid] += a;
            __syncthreads();
        }
        unsigned tot = s[255];
        if (i < NBLK_SCAN) bsum[i] = run + s[tid] - v;
        run += tot;
        __syncthreads();
    }
}

// Scan level 3: add block carries; also copy off -> cur (scatter cursors).
__global__ void scan3_kernel(unsigned* __restrict__ off,
                             const unsigned* __restrict__ bsum,
                             unsigned* __restrict__ cur) {
    int i = blockIdx.x * blockDim.x + threadIdx.x;
    if (i >= TBMn) return;
    unsigned o = off[i] + bsum[i >> 10];
    off[i] = o;
    cur[i] = o;
}

// Place each valid pixel id into its cell's list segment (1 int atomic/pixel).
__global__ void scatter_kernel(const int* __restrict__ cellid,
                               unsigned* __restrict__ cur,
                               unsigned* __restrict__ list) {
    int g = blockIdx.x * blockDim.x + threadIdx.x;
    if (g >= Pn) return;
    int c = cellid[g];
    if (c < 0) return;
    unsigned pos = atomicAdd(&cur[c], 1u);
    list[pos] = (unsigned)g;
}

// Per cell: carry lmap(20)+crop(20) in registers across T steps; sem sums are
// GATHERED from the binned pixel records (no atomics).
__global__ void update_kernel(const float* __restrict__ g_exp,
                              const float* __restrict__ g_obst,
                              const unsigned* __restrict__ cnt,
                              const unsigned* __restrict__ off,
                              const unsigned* __restrict__ list,
                              const float* __restrict__ rec,
                              const int* __restrict__ done_flags,
                              const int* __restrict__ upd_flags,
                              const float* __restrict__ ws_lpose,
                              const float* __restrict__ init_lmap,
                              const float* __restrict__ init_gmap,
                              const int* __restrict__ init_bounds,
                              float* __restrict__ out_feats,
                              float* __restrict__ out_lmap,
                              float* __restrict__ out_gmap) {
#pragma clang fp contract(off)
    int idx = blockIdx.x * blockDim.x + threadIdx.x;
    if (idx >= Bn * M2n) return;
    int b = idx / M2n, j = idx % M2n;
    int y = j / LOCAL_Mn, x = j % LOCAL_Mn;
    int y1 = init_bounds[b * 4 + 0];
    int x1 = init_bounds[b * 4 + 2];

    float lm[MAP_CHn], cr[MAP_CHn];
#pragma unroll
    for (int ch = 0; ch < MAP_CHn; ch++)
        lm[ch] = init_lmap[((size_t)(b * MAP_CHn + ch)) * M2n + j];
#pragma unroll
    for (int ch = 0; ch < MAP_CHn; ch++)
        cr[ch] = init_gmap[((size_t)(b * MAP_CHn + ch) * GLOBAL_Mn + (y1 + y)) * GLOBAL_Mn + (x1 + x)];

    for (int t = 0; t < Tn; t++) {
        int done = done_flags[b * Tn + t];
        int upd  = upd_flags[b * Tn + t];
        if (done) {
#pragma unroll
            for (int ch = 0; ch < MAP_CHn; ch++) { lm[ch] = 0.0f; cr[ch] = 0.0f; }
        }
        float lx = ws_lpose[(t * Bn + b) * 3 + 0];
        float ly = ws_lpose[(t * Bn + b) * 3 + 1];
        float dxg = (float)x - lx / 5.0f;
        float dyg = (float)y - ly / 5.0f;
        float d2 = dxg * dxg + dyg * dyg;
        float agent = (d2 <= 4.0f) ? 1.0f : 0.0f;
        float close = (d2 <= 9.0f) ? 1.0f : 0.0f;

        int cell = (t * Bn + b) * M2n + j;
        float expv  = g_exp[cell];
        float obstv = g_obst[cell];
        lm[0] = fmaxf(lm[0], fminf(fmaxf(obstv, 0.0f), 1.0f));
        lm[1] = fmaxf(lm[1], fminf(fmaxf(expv, 0.0f), 1.0f));
        lm[2] = agent;
        lm[3] = fmaxf(lm[3], close);

        // gather sem sums from binned pixel records
        float sem[CATn];
#pragma unroll
        for (int c = 0; c < CATn; c++) sem[c] = 0.0f;
        unsigned n = cnt[cell];
        unsigned st = off[cell];
        for (unsigned k = 0; k < n; k++) {
            unsigned g = list[st + k];
            const float4* rp = (const float4*)(rec + (size_t)g * CATn);
            float4 r0 = rp[0], r1 = rp[1], r2 = rp[2], r3 = rp[3];
            sem[0] += r0.x;  sem[1] += r0.y;  sem[2] += r0.z;  sem[3] += r0.w;
            sem[4] += r1.x;  sem[5] += r1.y;  sem[6] += r1.z;  sem[7] += r1.w;
            sem[8] += r2.x;  sem[9] += r2.y;  sem[10] += r2.z; sem[11] += r2.w;
            sem[12] += r3.x; sem[13] += r3.y; sem[14] += r3.z; sem[15] += r3.w;
        }
#pragma unroll
        for (int c = 0; c < CATn; c++)
            lm[NON_SEMn + c] = fmaxf(lm[NON_SEMn + c], fminf(fmaxf(sem[c], 0.0f), 1.0f));
        if (upd) {
#pragma unroll
            for (int ch = 0; ch < MAP_CHn; ch++) cr[ch] = fmaxf(cr[ch], lm[ch]);
        }

        size_t fb = ((size_t)(b * Tn + t) * FEAT_CHn) * M2n + j;
#pragma unroll
        for (int ch = 0; ch < NON_SEMn; ch++) out_feats[fb + (size_t)ch * M2n] = lm[ch];
#pragma unroll
        for (int ch = 0; ch < NON_SEMn; ch++) out_feats[fb + (size_t)(NON_SEMn + ch) * M2n] = cr[ch];
#pragma unroll
        for (int c = 0; c < CATn; c++) out_feats[fb + (size_t)(2 * NON_SEMn + c) * M2n] = lm[NON_SEMn + c];
    }

#pragma unroll
    for (int ch = 0; ch < MAP_CHn; ch++)
        out_lmap[((size_t)(b * MAP_CHn + ch)) * M2n + j] = lm[ch];
#pragma unroll
    for (int ch = 0; ch < MAP_CHn; ch++)
        out_gmap[((size_t)(b * MAP_CHn + ch) * GLOBAL_Mn + (y1 + y)) * GLOBAL_Mn + (x1 + x)] = cr[ch];
}

// Outside-window global map, float4-vectorized.
__global__ void final_gmap_kernel(const float* __restrict__ init_gmap,
                                  const int* __restrict__ init_bounds,
                                  const float* __restrict__ anydone,
                                  float* __restrict__ out_gmap) {
    size_t i4 = (size_t)blockIdx.x * blockDim.x + threadIdx.x;
    const size_t total4 = (size_t)Bn * MAP_CHn * GLOBAL_Mn * GLOBAL_Mn / 4;
    if (i4 >= total4) return;
    size_t f = i4 * 4;
    int gx = (int)(f % GLOBAL_Mn);
    size_t r = f / GLOBAL_Mn;
    int gy = (int)(r % GLOBAL_Mn);
    size_t bc = r / GLOBAL_Mn;
    int b = (int)(bc / MAP_CHn);
    int y1 = init_bounds[b * 4 + 0];
    int x1 = init_bounds[b * 4 + 2];
    if (gy >= y1 && gy < y1 + LOCAL_Mn && gx >= x1 && gx < x1 + LOCAL_Mn) return;
    float4 v;
    if (anydone[b] != 0.0f) {
        v = make_float4(0.0f, 0.0f, 0.0f, 0.0f);
    } else {
        v = *(const float4*)(init_gmap + f);
    }
    *(float4*)(out_gmap + f) = v;
}

// ---------------- launch ----------------
extern "C" void kernel_launch(void* const* d_in, const int* in_sizes, int n_in,
                              void* d_out, int out_size, void* d_ws, size_t ws_size,
                              hipStream_t stream) {
    const float* obs        = (const float*)d_in[0];
    const float* pose_delta = (const float*)d_in[1];
    const int*   done_flags = (const int*)d_in[2];
    const int*   upd_flags  = (const int*)d_in[3];
    const float* cam_poses  = (const float*)d_in[4];
    const float* init_lmap  = (const float*)d_in[5];
    const float* init_gmap  = (const float*)d_in[6];
    const float* init_lpose = (const float*)d_in[7];
    const float* init_gpose = (const float*)d_in[8];
    const int*   init_bnds  = (const int*)d_in[9];
    const float* init_orgs  = (const float*)d_in[10];

    float* out = (float*)d_out;
    float* ws  = (float*)d_ws;

    float*    ws_lpose = ws + WS_LPOSE;
    float*    ws_anyd  = ws + WS_ANYD;
    float*    g_exp    = ws + WS_EXP;
    float*    g_obst   = ws + WS_OBST;
    unsigned* cnt      = (unsigned*)(ws + WS_CNT);
    unsigned* off      = (unsigned*)(ws + WS_OFF);
    unsigned* cur      = (unsigned*)(ws + WS_CUR);
    unsigned* bsum     = (unsigned*)(ws + WS_BSUM);
    int*      cellid   = (int*)(ws + WS_CELL);
    unsigned* list     = (unsigned*)(ws + WS_LIST);
    float*    rec      = ws + WS_REC;

    float fx = (float)(160.0 / (2.0 * tan(79.0 * M_PI / 180.0 / 2.0)));

    pose_kernel<<<1, 64, 0, stream>>>(pose_delta, done_flags, upd_flags,
                                      init_lpose, init_gpose, init_bnds, init_orgs,
                                      ws_lpose, ws_anyd,
                                      out + OUT_LP, out + OUT_GP,
                                      out + OUT_BNDS, out + OUT_ORGS);

    // zero exp + obst + cnt (contiguous 3*TBM)
    hipMemsetAsync(g_exp, 0, (size_t)3 * TBMn * sizeof(float), stream);

    project_bin_kernel<<<(Pn + 255) / 256, 256, 0, stream>>>(
        obs, cam_poses, ws_lpose, g_exp, g_obst, cnt, cellid, rec, fx);

    scan1_kernel<<<NBLK_SCAN, 256, 0, stream>>>(cnt, off, bsum);
    scan2_kernel<<<1, 256, 0, stream>>>(bsum);
    scan3_kernel<<<(TBMn + 255) / 256, 256, 0, stream>>>(off, bsum, cur);

    scatter_kernel<<<(Pn + 255) / 256, 256, 0, stream>>>(cellid, cur, list);

    update_kernel<<<(Bn * M2n + 255) / 256, 256, 0, stream>>>(
        g_exp, g_obst, cnt, off, list, rec, done_flags, upd_flags, ws_lpose,
        init_lmap, init_gmap, init_bnds,
        out + OUT_FEATS, out + OUT_LMAP, out + OUT_GMAP);

    const size_t gmap_total4 = (size_t)Bn * MAP_CHn * GLOBAL_Mn * GLOBAL_Mn / 4;
    final_gmap_kernel<<<(int)((gmap_total4 + 255) / 256), 256, 0, stream>>>(
        init_gmap, init_bnds, ws_anyd, out + OUT_GMAP);
}

// Round 6
// 920.923 us; speedup vs baseline: 1.3529x; 1.0049x over previous
//
#include <hip/hip_runtime.h>
#include <math.h>

// ---------------- problem constants ----------------
#define Bn 4
#define Tn 8
#define Hn 120
#define Wn 160
#define HWn (Hn * Wn)
#define NON_SEMn 4
#define CATn 16
#define MAP_CHn 20
#define FEAT_CHn 24
#define LOCAL_Mn 240
#define GLOBAL_Mn 960
#define M2n (LOCAL_Mn * LOCAL_Mn)
#define TBMn (Tn * Bn * M2n)                  // 1,843,200 cells
#define Pn (Tn * Bn * HWn)                    // 614,400 pixels
#define NBLK_SCAN 1800                        // TBMn / 1024
#define UPD_BLKS ((Bn * M2n + 255) / 256)     // 900
#define GMAP_BLKS ((Bn * MAP_CHn * GLOBAL_Mn * GLOBAL_Mn / 4 + 255) / 256) // 72000

#define DEG2RADf ((float)0.017453292519943295)

typedef float vf4 __attribute__((ext_vector_type(4)));  // NT-builtin-compatible

// output layout (float element offsets into d_out)
#define OUT_FEATS 0
#define OUT_LMAP  44236800
#define OUT_GMAP  48844800
#define OUT_LP    122572800
#define OUT_GP    122572896
#define OUT_BNDS  122572992
#define OUT_ORGS  122573120

// workspace layout (4-byte element offsets into d_ws)
// rec4[cell] = {exp(f32), obst(f32), cnt(u32), cur(u32)} — one 16B record,
// so a pixel's bookkeeping (2 stores + 1 atomic) hits ONE cache line.
#define WS_LPOSE  0                           // T*B*3 = 96
#define WS_ANYD   96                          // B, padded to 128 (512B align)
#define WS_REC4   128                         // TBM uint4 = 4*TBM dwords
#define WS_BSUM   (WS_REC4 + 4 * TBMn)        // 1800, pad 2048
#define WS_CELL   (WS_BSUM + 2048)            // P int
#define WS_LIST   (WS_CELL + Pn)              // P uint
#define WS_RECS   (WS_LIST + Pn)              // P*16 floats (sem records)

// ---------------- kernels ----------------

__global__ void pose_kernel(const float* __restrict__ pose_delta,
                            const int* __restrict__ done_flags,
                            const int* __restrict__ upd_flags,
                            const float* __restrict__ init_lpose,
                            const float* __restrict__ init_gpose,
                            const int* __restrict__ init_bounds,
                            const float* __restrict__ init_origins,
                            float* __restrict__ ws_lpose,
                            float* __restrict__ ws_anydone,
                            float* __restrict__ out_lp,
                            float* __restrict__ out_gp,
                            float* __restrict__ out_bnds,
                            float* __restrict__ out_orgs) {
#pragma clang fp contract(off)
    int b = threadIdx.x;
    if (b >= Bn) return;
    float lx = init_lpose[b * 3 + 0], ly = init_lpose[b * 3 + 1], lz = init_lpose[b * 3 + 2];
    float gx = init_gpose[b * 3 + 0], gy = init_gpose[b * 3 + 1], gz = init_gpose[b * 3 + 2];
    int b0 = init_bounds[b * 4 + 0], b1 = init_bounds[b * 4 + 1];
    int b2i = init_bounds[b * 4 + 2], b3 = init_bounds[b * 4 + 3];
    float ox = init_origins[b * 3 + 0], oy = init_origins[b * 3 + 1], oz = init_origins[b * 3 + 2];
    float anyd = 0.0f;
    for (int t = 0; t < Tn; t++) {
        int done = done_flags[b * Tn + t];
        int upd  = upd_flags[b * Tn + t];
        if (done) {
            lx = 600.0f; ly = 600.0f; lz = 0.0f;
            gx = 2400.0f; gy = 2400.0f; gz = 0.0f;
            b0 = 360; b1 = 600; b2i = 360; b3 = 600;
            ox = 1800.0f; oy = 1800.0f; oz = 0.0f;
            anyd = 1.0f;
        }
        float th = lz * DEG2RADf;
        float c = cosf(th), s = sinf(th);
        float d0 = pose_delta[(b * Tn + t) * 3 + 0];
        float d1 = pose_delta[(b * Tn + t) * 3 + 1];
        float d2 = pose_delta[(b * Tn + t) * 3 + 2];
        lx = lx + (d0 * c - d1 * s);
        ly = ly + (d0 * s + d1 * c);
        lz = lz + d2;
        if (upd) { gx = lx + ox; gy = ly + oy; gz = lz + oz; }
        ws_lpose[(t * Bn + b) * 3 + 0] = lx;
        ws_lpose[(t * Bn + b) * 3 + 1] = ly;
        ws_lpose[(t * Bn + b) * 3 + 2] = lz;
        out_lp[(b * Tn + t) * 3 + 0] = lx;
        out_lp[(b * Tn + t) * 3 + 1] = ly;
        out_lp[(b * Tn + t) * 3 + 2] = lz;
        out_gp[(b * Tn + t) * 3 + 0] = gx;
        out_gp[(b * Tn + t) * 3 + 1] = gy;
        out_gp[(b * Tn + t) * 3 + 2] = gz;
        out_bnds[(b * Tn + t) * 4 + 0] = (float)b0;
        out_bnds[(b * Tn + t) * 4 + 1] = (float)b1;
        out_bnds[(b * Tn + t) * 4 + 2] = (float)b2i;
        out_bnds[(b * Tn + t) * 4 + 3] = (float)b3;
        out_orgs[(b * Tn + t) * 3 + 0] = ox;
        out_orgs[(b * Tn + t) * 3 + 1] = oy;
        out_orgs[(b * Tn + t) * 3 + 2] = oz;
    }
    ws_anydone[b] = anyd;
}

// Per pixel: project; write 64B sem record (coalesced); all cell bookkeeping
// (exp store, obst store, cnt atomic) hits ONE 16B record -> one cache line.
__global__ void project_bin_kernel(const float* __restrict__ obs,
                                   const float* __restrict__ cam,
                                   const float* __restrict__ ws_lpose,
                                   uint4* __restrict__ rec4,
                                   int* __restrict__ cellid,
                                   float* __restrict__ recs,
                                   float fx) {
#pragma clang fp contract(off)
    int g = blockIdx.x * blockDim.x + threadIdx.x;
    if (g >= Pn) return;
    int p = g % HWn;
    int tb = g / HWn;
    int b = tb % Bn;
    int t = tb / Bn;
    int h = p / Wn, w = p % Wn;
    const float* ob = obs + (size_t)((b * Tn + t) * MAP_CHn) * HWn;
    float depth = ob[3 * HWn + p] * 400.0f + 50.0f;
    float u = (float)w - 80.0f;
    float v = 60.0f - (float)h;
    float px = u * depth / fx;
    float py = v * depth / fx;
    float pz = depth;
    const float* Tm = cam + (size_t)(b * Tn + t) * 16;
    float X = ((Tm[0] * px + Tm[1] * py) + Tm[2] * pz) + Tm[3];
    float Y = ((Tm[4] * px + Tm[5] * py) + Tm[6] * pz) + Tm[7];
    float Z = ((Tm[8] * px + Tm[9] * py) + Tm[10] * pz) + Tm[11];
    float x_f = Z;
    float y_l = -X;
    float z_u = Y + 88.0f;
    float lx = ws_lpose[(t * Bn + b) * 3 + 0];
    float ly = ws_lpose[(t * Bn + b) * 3 + 1];
    float lz = ws_lpose[(t * Bn + b) * 3 + 2];
    float th2 = lz * DEG2RADf;
    float c2 = cosf(th2), s2 = sinf(th2);
    float wx = (lx + x_f * c2) - y_l * s2;
    float wy = (ly + x_f * s2) + y_l * c2;
    int ix = (int)floorf(wx / 5.0f);
    int iy = (int)floorf(wy / 5.0f);
    bool valid = (depth > 25.0f) && (depth < 500.0f) &&
                 (ix >= 0) && (ix < LOCAL_Mn) && (iy >= 0) && (iy < LOCAL_Mn);

    // sem record: 16 coalesced channel reads -> one 64B record per pixel
    vf4 r[4];
#pragma unroll
    for (int q = 0; q < 4; q++) {
        r[q].x = ob[(size_t)(NON_SEMn + 4 * q + 0) * HWn + p];
        r[q].y = ob[(size_t)(NON_SEMn + 4 * q + 1) * HWn + p];
        r[q].z = ob[(size_t)(NON_SEMn + 4 * q + 2) * HWn + p];
        r[q].w = ob[(size_t)(NON_SEMn + 4 * q + 3) * HWn + p];
    }
    vf4* rp = (vf4*)(recs + (size_t)g * CATn);
#pragma unroll
    for (int q = 0; q < 4; q++)
        __builtin_nontemporal_store(r[q], rp + q);

    int cell = -1;
    if (valid) {
        cell = (t * Bn + b) * M2n + iy * LOCAL_Mn + ix;
        float* rf = (float*)&rec4[cell];
        rf[0] = 1.0f;                                    // exp hit
        if (z_u > 25.0f && z_u < 150.0f) rf[1] = 1.0f;   // obst hit
        atomicAdd(((unsigned*)&rec4[cell]) + 2, 1u);     // cnt, same line
    }
    cellid[g] = cell;
}

// Scan level 1: block scans 1024 cnt values (256 thr x 4 cells, coalesced
// uint4 loads); local exclusive prefix -> rec4[].w; block total -> bsum.
__global__ void scan1_kernel(uint4* __restrict__ rec4,
                             unsigned* __restrict__ bsum) {
    __shared__ unsigned s[256];
    int tid = threadIdx.x;
    int base = blockIdx.x * 1024 + tid * 4;
    uint4 r0 = rec4[base], r1 = rec4[base + 1], r2 = rec4[base + 2], r3 = rec4[base + 3];
    unsigned v0 = r0.z, v1 = r1.z, v2 = r2.z, v3 = r3.z;
    unsigned tsum = v0 + v1 + v2 + v3;
    s[tid] = tsum;
    __syncthreads();
    for (int d = 1; d < 256; d <<= 1) {
        unsigned a = (tid >= d) ? s[tid - d] : 0u;
        __syncthreads();
        s[tid] += a;
        __syncthreads();
    }
    unsigned excl = s[tid] - tsum;
    if (tid == 255) bsum[blockIdx.x] = s[255];
    ((unsigned*)&rec4[base])[3]     = excl;
    ((unsigned*)&rec4[base + 1])[3] = excl + v0;
    ((unsigned*)&rec4[base + 2])[3] = excl + v0 + v1;
    ((unsigned*)&rec4[base + 3])[3] = excl + v0 + v1 + v2;
}

// Scan level 2+3 merged: each block computes its own carry (sum of preceding
// bsum) by parallel reduce, then adds it to its 1024 rec4[].w fields.
__global__ void scan_carry_kernel(uint4* __restrict__ rec4,
                                  const unsigned* __restrict__ bsum) {
    __shared__ unsigned ls[256];
    int tid = threadIdx.x;
    unsigned part = 0;
    for (int i = tid; i < (int)blockIdx.x; i += 256) part += bsum[i];
    ls[tid] = part;
    __syncthreads();
    for (int d = 128; d > 0; d >>= 1) {
        if (tid < d) ls[tid] += ls[tid + d];
        __syncthreads();
    }
    unsigned carry = ls[0];
    if (carry == 0) return;
    int base = blockIdx.x * 1024 + tid * 4;
#pragma unroll
    for (int k = 0; k < 4; k++) {
        unsigned* wp = ((unsigned*)&rec4[base + k]) + 3;
        *wp = *wp + carry;
    }
}

// Place each valid pixel id into its cell's list segment (1 int atomic/pixel,
// on the cell's record line). Afterwards rec4.w == off + cnt.
__global__ void scatter_kernel(const int* __restrict__ cellid,
                               uint4* __restrict__ rec4,
                               unsigned* __restrict__ list) {
    int g = blockIdx.x * blockDim.x + threadIdx.x;
    if (g >= Pn) return;
    int c = cellid[g];
    if (c < 0) return;
    unsigned pos = atomicAdd(((unsigned*)&rec4[c]) + 3, 1u);
    list[pos] = (unsigned)g;
}

// Mega kernel: blocks [0, UPD_BLKS) run the per-cell T-step update (gathered
// sem sums, zero atomics); blocks [UPD_BLKS, +GMAP_BLKS) stream the
// outside-window global map. Fusing overlaps the latency-bound gather phase
// with the BW-bound copy. All pure-output writes are nontemporal.
__global__ void __launch_bounds__(256)
mega_kernel(const uint4* __restrict__ rec4,
            const unsigned* __restrict__ list,
            const float* __restrict__ recs,
            const int* __restrict__ done_flags,
            const int* __restrict__ upd_flags,
            const float* __restrict__ ws_lpose,
            const float* __restrict__ init_lmap,
            const float* __restrict__ init_gmap,
            const int* __restrict__ init_bounds,
            const float* __restrict__ anydone,
            float* __restrict__ out_feats,
            float* __restrict__ out_lmap,
            float* __restrict__ out_gmap) {
#pragma clang fp contract(off)
    if (blockIdx.x >= UPD_BLKS) {
        // ---- gmap copy path ----
        size_t i4 = (size_t)(blockIdx.x - UPD_BLKS) * blockDim.x + threadIdx.x;
        const size_t total4 = (size_t)Bn * MAP_CHn * GLOBAL_Mn * GLOBAL_Mn / 4;
        if (i4 >= total4) return;
        size_t f = i4 * 4;
        int gx = (int)(f % GLOBAL_Mn);
        size_t r = f / GLOBAL_Mn;
        int gy = (int)(r % GLOBAL_Mn);
        size_t bc = r / GLOBAL_Mn;
        int b = (int)(bc / MAP_CHn);
        int y1 = init_bounds[b * 4 + 0];
        int x1 = init_bounds[b * 4 + 2];
        if (gy >= y1 && gy < y1 + LOCAL_Mn && gx >= x1 && gx < x1 + LOCAL_Mn) return;
        vf4 v;
        if (anydone[b] != 0.0f) {
            v = (vf4)(0.0f);
        } else {
            v = __builtin_nontemporal_load((const vf4*)(init_gmap + f));
        }
        __builtin_nontemporal_store(v, (vf4*)(out_gmap + f));
        return;
    }

    // ---- update path ----
    int idx = blockIdx.x * blockDim.x + threadIdx.x;
    if (idx >= Bn * M2n) return;
    int b = idx / M2n, j = idx % M2n;
    int y = j / LOCAL_Mn, x = j % LOCAL_Mn;
    int y1 = init_bounds[b * 4 + 0];
    int x1 = init_bounds[b * 4 + 2];

    float lm[MAP_CHn], cr[MAP_CHn];
#pragma unroll
    for (int ch = 0; ch < MAP_CHn; ch++)
        lm[ch] = __builtin_nontemporal_load(init_lmap + ((size_t)(b * MAP_CHn + ch)) * M2n + j);
#pragma unroll
    for (int ch = 0; ch < MAP_CHn; ch++)
        cr[ch] = __builtin_nontemporal_load(
            init_gmap + ((size_t)(b * MAP_CHn + ch) * GLOBAL_Mn + (y1 + y)) * GLOBAL_Mn + (x1 + x));

    for (int t = 0; t < Tn; t++) {
        int done = done_flags[b * Tn + t];
        int upd  = upd_flags[b * Tn + t];
        if (done) {
#pragma unroll
            for (int ch = 0; ch < MAP_CHn; ch++) { lm[ch] = 0.0f; cr[ch] = 0.0f; }
        }
        float lx = ws_lpose[(t * Bn + b) * 3 + 0];
        float ly = ws_lpose[(t * Bn + b) * 3 + 1];
        float dxg = (float)x - lx / 5.0f;
        float dyg = (float)y - ly / 5.0f;
        float d2 = dxg * dxg + dyg * dyg;
        float agent = (d2 <= 4.0f) ? 1.0f : 0.0f;
        float close = (d2 <= 9.0f) ? 1.0f : 0.0f;

        int cell = (t * Bn + b) * M2n + j;
        uint4 rc = rec4[cell];          // {exp, obst, cnt, end} in one load
        float expv  = __uint_as_float(rc.x);
        float obstv = __uint_as_float(rc.y);
        unsigned n  = rc.z;
        unsigned st = rc.w - n;         // scatter left w == off + cnt
        lm[0] = fmaxf(lm[0], fminf(fmaxf(obstv, 0.0f), 1.0f));
        lm[1] = fmaxf(lm[1], fminf(fmaxf(expv, 0.0f), 1.0f));
        lm[2] = agent;
        lm[3] = fmaxf(lm[3], close);

        float sem[CATn];
#pragma unroll
        for (int c = 0; c < CATn; c++) sem[c] = 0.0f;
        for (unsigned k = 0; k < n; k++) {
            unsigned g = list[st + k];
            const vf4* rp = (const vf4*)(recs + (size_t)g * CATn);
            vf4 r0 = rp[0], r1 = rp[1], r2 = rp[2], r3 = rp[3];
            sem[0] += r0.x;  sem[1] += r0.y;  sem[2] += r0.z;  sem[3] += r0.w;
            sem[4] += r1.x;  sem[5] += r1.y;  sem[6] += r1.z;  sem[7] += r1.w;
            sem[8] += r2.x;  sem[9] += r2.y;  sem[10] += r2.z; sem[11] += r2.w;
            sem[12] += r3.x; sem[13] += r3.y; sem[14] += r3.z; sem[15] += r3.w;
        }
#pragma unroll
        for (int c = 0; c < CATn; c++)
            lm[NON_SEMn + c] = fmaxf(lm[NON_SEMn + c], fminf(fmaxf(sem[c], 0.0f), 1.0f));
        if (upd) {
#pragma unroll
            for (int ch = 0; ch < MAP_CHn; ch++) cr[ch] = fmaxf(cr[ch], lm[ch]);
        }

        size_t fb = ((size_t)(b * Tn + t) * FEAT_CHn) * M2n + j;
#pragma unroll
        for (int ch = 0; ch < NON_SEMn; ch++)
            __builtin_nontemporal_store(lm[ch], out_feats + fb + (size_t)ch * M2n);
#pragma unroll
        for (int ch = 0; ch < NON_SEMn; ch++)
            __builtin_nontemporal_store(cr[ch], out_feats + fb + (size_t)(NON_SEMn + ch) * M2n);
#pragma unroll
        for (int c = 0; c < CATn; c++)
            __builtin_nontemporal_store(lm[NON_SEMn + c], out_feats + fb + (size_t)(2 * NON_SEMn + c) * M2n);
    }

#pragma unroll
    for (int ch = 0; ch < MAP_CHn; ch++)
        __builtin_nontemporal_store(lm[ch], out_lmap + ((size_t)(b * MAP_CHn + ch)) * M2n + j);
#pragma unroll
    for (int ch = 0; ch < MAP_CHn; ch++)
        __builtin_nontemporal_store(
            cr[ch], out_gmap + ((size_t)(b * MAP_CHn + ch) * GLOBAL_Mn + (y1 + y)) * GLOBAL_Mn + (x1 + x));
}

// ---------------- launch ----------------
extern "C" void kernel_launch(void* const* d_in, const int* in_sizes, int n_in,
                              void* d_out, int out_size, void* d_ws, size_t ws_size,
                              hipStream_t stream) {
    const float* obs        = (const float*)d_in[0];
    const float* pose_delta = (const float*)d_in[1];
    const int*   done_flags = (const int*)d_in[2];
    const int*   upd_flags  = (const int*)d_in[3];
    const float* cam_poses  = (const float*)d_in[4];
    const float* init_lmap  = (const float*)d_in[5];
    const float* init_gmap  = (const float*)d_in[6];
    const float* init_lpose = (const float*)d_in[7];
    const float* init_gpose = (const float*)d_in[8];
    const int*   init_bnds  = (const int*)d_in[9];
    const float* init_orgs  = (const float*)d_in[10];

    float* out = (float*)d_out;
    float* ws  = (float*)d_ws;

    float*    ws_lpose = ws + WS_LPOSE;
    float*    ws_anyd  = ws + WS_ANYD;
    uint4*    rec4     = (uint4*)(ws + WS_REC4);
    unsigned* bsum     = (unsigned*)(ws + WS_BSUM);
    int*      cellid   = (int*)(ws + WS_CELL);
    unsigned* list     = (unsigned*)(ws + WS_LIST);
    float*    recs     = ws + WS_RECS;

    float fx = (float)(160.0 / (2.0 * tan(79.0 * M_PI / 180.0 / 2.0)));

    pose_kernel<<<1, 64, 0, stream>>>(pose_delta, done_flags, upd_flags,
                                      init_lpose, init_gpose, init_bnds, init_orgs,
                                      ws_lpose, ws_anyd,
                                      out + OUT_LP, out + OUT_GP,
                                      out + OUT_BNDS, out + OUT_ORGS);

    (void)hipMemsetAsync(rec4, 0, (size_t)TBMn * sizeof(uint4), stream);

    project_bin_kernel<<<(Pn + 255) / 256, 256, 0, stream>>>(
        obs, cam_poses, ws_lpose, rec4, cellid, recs, fx);

    scan1_kernel<<<NBLK_SCAN, 256, 0, stream>>>(rec4, bsum);
    scan_carry_kernel<<<NBLK_SCAN, 256, 0, stream>>>(rec4, bsum);

    scatter_kernel<<<(Pn + 255) / 256, 256, 0, stream>>>(cellid, rec4, list);

    mega_kernel<<<UPD_BLKS + GMAP_BLKS, 256, 0, stream>>>(
        rec4, list, recs, done_flags, upd_flags, ws_lpose,
        init_lmap, init_gmap, init_bnds, ws_anyd,
        out + OUT_FEATS, out + OUT_LMAP, out + OUT_GMAP);
}

// Round 7
// 837.367 us; speedup vs baseline: 1.4879x; 1.0998x over previous
//
#include <hip/hip_runtime.h>
#include <math.h>

// ---------------- problem constants ----------------
#define Bn 4
#define Tn 8
#define Hn 120
#define Wn 160
#define HWn (Hn * Wn)
#define NON_SEMn 4
#define CATn 16
#define MAP_CHn 20
#define FEAT_CHn 24
#define LOCAL_Mn 240
#define GLOBAL_Mn 960
#define M2n (LOCAL_Mn * LOCAL_Mn)
#define TBMn (Tn * Bn * M2n)                  // 1,843,200 cells
#define Pn (Tn * Bn * HWn)                    // 614,400 pixels
#define NBLK_SCAN 1800                        // TBMn / 1024
#define UPD_BLKS ((Bn * M2n + 255) / 256)     // 900
#define GMAP_BLKS ((Bn * MAP_CHn * GLOBAL_Mn * GLOBAL_Mn / 4 + 255) / 256) // 72000

#define DEG2RADf ((float)0.017453292519943295)

typedef float vf4 __attribute__((ext_vector_type(4)));  // NT-builtin-compatible

// output layout (float element offsets into d_out)
#define OUT_FEATS 0
#define OUT_LMAP  44236800
#define OUT_GMAP  48844800
#define OUT_LP    122572800
#define OUT_GP    122572896
#define OUT_BNDS  122572992
#define OUT_ORGS  122573120

// workspace layout (4-byte element offsets into d_ws)
// rec2[cell] = {packed counts (n bits0-15, obst_n bits16-30), cur(u32)} — 8B.
// exp == (n>0), obst == (obst_n>0), so ONE atomicAdd per pixel does all cell
// bookkeeping, and the atomic dirty set (14.7 MB) stays L2-resident.
#define WS_LPOSE  0                           // T*B*3 = 96
#define WS_ANYD   96                          // B, padded to 128
#define WS_REC2   128                         // TBM uint2 = 2*TBM dwords
#define WS_BSUM   (WS_REC2 + 2 * TBMn)        // 1800, pad 2048
#define WS_CELL   (WS_BSUM + 2048)            // P int
#define WS_RECB   (WS_CELL + Pn)              // P*16 floats (binned sem records)

// ---------------- kernels ----------------

__global__ void pose_kernel(const float* __restrict__ pose_delta,
                            const int* __restrict__ done_flags,
                            const int* __restrict__ upd_flags,
                            const float* __restrict__ init_lpose,
                            const float* __restrict__ init_gpose,
                            const int* __restrict__ init_bounds,
                            const float* __restrict__ init_origins,
                            float* __restrict__ ws_lpose,
                            float* __restrict__ ws_anydone,
                            float* __restrict__ out_lp,
                            float* __restrict__ out_gp,
                            float* __restrict__ out_bnds,
                            float* __restrict__ out_orgs) {
#pragma clang fp contract(off)
    int b = threadIdx.x;
    if (b >= Bn) return;
    float lx = init_lpose[b * 3 + 0], ly = init_lpose[b * 3 + 1], lz = init_lpose[b * 3 + 2];
    float gx = init_gpose[b * 3 + 0], gy = init_gpose[b * 3 + 1], gz = init_gpose[b * 3 + 2];
    int b0 = init_bounds[b * 4 + 0], b1 = init_bounds[b * 4 + 1];
    int b2i = init_bounds[b * 4 + 2], b3 = init_bounds[b * 4 + 3];
    float ox = init_origins[b * 3 + 0], oy = init_origins[b * 3 + 1], oz = init_origins[b * 3 + 2];
    float anyd = 0.0f;
    for (int t = 0; t < Tn; t++) {
        int done = done_flags[b * Tn + t];
        int upd  = upd_flags[b * Tn + t];
        if (done) {
            lx = 600.0f; ly = 600.0f; lz = 0.0f;
            gx = 2400.0f; gy = 2400.0f; gz = 0.0f;
            b0 = 360; b1 = 600; b2i = 360; b3 = 600;
            ox = 1800.0f; oy = 1800.0f; oz = 0.0f;
            anyd = 1.0f;
        }
        float th = lz * DEG2RADf;
        float c = cosf(th), s = sinf(th);
        float d0 = pose_delta[(b * Tn + t) * 3 + 0];
        float d1 = pose_delta[(b * Tn + t) * 3 + 1];
        float d2 = pose_delta[(b * Tn + t) * 3 + 2];
        lx = lx + (d0 * c - d1 * s);
        ly = ly + (d0 * s + d1 * c);
        lz = lz + d2;
        if (upd) { gx = lx + ox; gy = ly + oy; gz = lz + oz; }
        ws_lpose[(t * Bn + b) * 3 + 0] = lx;
        ws_lpose[(t * Bn + b) * 3 + 1] = ly;
        ws_lpose[(t * Bn + b) * 3 + 2] = lz;
        out_lp[(b * Tn + t) * 3 + 0] = lx;
        out_lp[(b * Tn + t) * 3 + 1] = ly;
        out_lp[(b * Tn + t) * 3 + 2] = lz;
        out_gp[(b * Tn + t) * 3 + 0] = gx;
        out_gp[(b * Tn + t) * 3 + 1] = gy;
        out_gp[(b * Tn + t) * 3 + 2] = gz;
        out_bnds[(b * Tn + t) * 4 + 0] = (float)b0;
        out_bnds[(b * Tn + t) * 4 + 1] = (float)b1;
        out_bnds[(b * Tn + t) * 4 + 2] = (float)b2i;
        out_bnds[(b * Tn + t) * 4 + 3] = (float)b3;
        out_orgs[(b * Tn + t) * 3 + 0] = ox;
        out_orgs[(b * Tn + t) * 3 + 1] = oy;
        out_orgs[(b * Tn + t) * 3 + 2] = oz;
    }
    ws_anydone[b] = anyd;
}

// Per pixel: project (reads ONLY the depth plane), one packed atomicAdd on the
// cell record, write cell id. No sem reads, no record writes here.
__global__ void project_kernel(const float* __restrict__ obs,
                               const float* __restrict__ cam,
                               const float* __restrict__ ws_lpose,
                               uint2* __restrict__ rec2,
                               int* __restrict__ cellid,
                               float fx) {
#pragma clang fp contract(off)
    int g = blockIdx.x * blockDim.x + threadIdx.x;
    if (g >= Pn) return;
    int p = g % HWn;
    int tb = g / HWn;
    int b = tb % Bn;
    int t = tb / Bn;
    int h = p / Wn, w = p % Wn;
    const float* ob = obs + (size_t)((b * Tn + t) * MAP_CHn) * HWn;
    float depth = ob[3 * HWn + p] * 400.0f + 50.0f;
    float u = (float)w - 80.0f;
    float v = 60.0f - (float)h;
    float px = u * depth / fx;
    float py = v * depth / fx;
    float pz = depth;
    const float* Tm = cam + (size_t)(b * Tn + t) * 16;
    float X = ((Tm[0] * px + Tm[1] * py) + Tm[2] * pz) + Tm[3];
    float Y = ((Tm[4] * px + Tm[5] * py) + Tm[6] * pz) + Tm[7];
    float Z = ((Tm[8] * px + Tm[9] * py) + Tm[10] * pz) + Tm[11];
    float x_f = Z;
    float y_l = -X;
    float z_u = Y + 88.0f;
    float lx = ws_lpose[(t * Bn + b) * 3 + 0];
    float ly = ws_lpose[(t * Bn + b) * 3 + 1];
    float lz = ws_lpose[(t * Bn + b) * 3 + 2];
    float th2 = lz * DEG2RADf;
    float c2 = cosf(th2), s2 = sinf(th2);
    float wx = (lx + x_f * c2) - y_l * s2;
    float wy = (ly + x_f * s2) + y_l * c2;
    int ix = (int)floorf(wx / 5.0f);
    int iy = (int)floorf(wy / 5.0f);
    bool valid = (depth > 25.0f) && (depth < 500.0f) &&
                 (ix >= 0) && (ix < LOCAL_Mn) && (iy >= 0) && (iy < LOCAL_Mn);
    int cell = -1;
    if (valid) {
        cell = (t * Bn + b) * M2n + iy * LOCAL_Mn + ix;
        unsigned addv = 1u + ((z_u > 25.0f && z_u < 150.0f) ? 65536u : 0u);
        atomicAdd(&rec2[cell].x, addv);   // n in bits 0-15, obst_n in 16-30
    }
    cellid[g] = cell;
}

// Scan level 1: block scans 1024 cnt values; local exclusive prefix -> .y;
// block total -> bsum.
__global__ void scan1_kernel(uint2* __restrict__ rec2,
                             unsigned* __restrict__ bsum) {
    __shared__ unsigned s[256];
    int tid = threadIdx.x;
    int base = blockIdx.x * 1024 + tid * 4;
    unsigned v0 = rec2[base].x & 0xFFFFu, v1 = rec2[base + 1].x & 0xFFFFu;
    unsigned v2 = rec2[base + 2].x & 0xFFFFu, v3 = rec2[base + 3].x & 0xFFFFu;
    unsigned tsum = v0 + v1 + v2 + v3;
    s[tid] = tsum;
    __syncthreads();
    for (int d = 1; d < 256; d <<= 1) {
        unsigned a = (tid >= d) ? s[tid - d] : 0u;
        __syncthreads();
        s[tid] += a;
        __syncthreads();
    }
    unsigned excl = s[tid] - tsum;
    if (tid == 255) bsum[blockIdx.x] = s[255];
    rec2[base].y     = excl;
    rec2[base + 1].y = excl + v0;
    rec2[base + 2].y = excl + v0 + v1;
    rec2[base + 3].y = excl + v0 + v1 + v2;
}

// Scan level 2: single block exclusive-scans bsum[NBLK_SCAN] in place.
// Consumers add bsum[cell>>10] at use — no 29.5 MB carry pass.
__global__ void scan2_kernel(unsigned* __restrict__ bsum) {
    __shared__ unsigned s[256];
    int tid = threadIdx.x;
    unsigned run = 0;
    for (int base = 0; base < NBLK_SCAN; base += 256) {
        int i = base + tid;
        unsigned v = (i < NBLK_SCAN) ? bsum[i] : 0u;
        s[tid] = v;
        __syncthreads();
        for (int d = 1; d < 256; d <<= 1) {
            unsigned a = (tid >= d) ? s[tid - d] : 0u;
            __syncthreads();
            s[tid] += a;
            __syncthreads();
        }
        unsigned tot = s[255];
        if (i < NBLK_SCAN) bsum[i] = run + s[tid] - v;
        run += tot;
        __syncthreads();
    }
}

// Per pixel: read its 16 sem channels (coalesced plane reads) and write the
// 64B record DIRECTLY into its cell's binned segment (no list indirection).
__global__ void scatter_copy_kernel(const float* __restrict__ obs,
                                    const int* __restrict__ cellid,
                                    const unsigned* __restrict__ bsum,
                                    uint2* __restrict__ rec2,
                                    float* __restrict__ recb) {
    int g = blockIdx.x * blockDim.x + threadIdx.x;
    if (g >= Pn) return;
    int c = cellid[g];
    if (c < 0) return;
    int p = g % HWn;
    int tb = g / HWn;
    int b = tb % Bn;
    int t = tb / Bn;
    const float* ob = obs + (size_t)((b * Tn + t) * MAP_CHn) * HWn;
    vf4 r[4];
#pragma unroll
    for (int q = 0; q < 4; q++) {
        r[q].x = ob[(size_t)(NON_SEMn + 4 * q + 0) * HWn + p];
        r[q].y = ob[(size_t)(NON_SEMn + 4 * q + 1) * HWn + p];
        r[q].z = ob[(size_t)(NON_SEMn + 4 * q + 2) * HWn + p];
        r[q].w = ob[(size_t)(NON_SEMn + 4 * q + 3) * HWn + p];
    }
    unsigned pos = bsum[c >> 10] + atomicAdd(&rec2[c].y, 1u);
    vf4* rp = (vf4*)(recb + (size_t)pos * CATn);
#pragma unroll
    for (int q = 0; q < 4; q++)
        __builtin_nontemporal_store(r[q], rp + q);
}

// Mega kernel: blocks [0, UPD_BLKS) run the per-cell T-step update (gathered
// sem sums from contiguous binned segments, zero atomics); the rest stream
// the outside-window global map.
__global__ void __launch_bounds__(256)
mega_kernel(const uint2* __restrict__ rec2,
            const unsigned* __restrict__ bsum,
            const float* __restrict__ recb,
            const int* __restrict__ done_flags,
            const int* __restrict__ upd_flags,
            const float* __restrict__ ws_lpose,
            const float* __restrict__ init_lmap,
            const float* __restrict__ init_gmap,
            const int* __restrict__ init_bounds,
            const float* __restrict__ anydone,
            float* __restrict__ out_feats,
            float* __restrict__ out_lmap,
            float* __restrict__ out_gmap) {
#pragma clang fp contract(off)
    if (blockIdx.x >= UPD_BLKS) {
        // ---- gmap copy path ----
        size_t i4 = (size_t)(blockIdx.x - UPD_BLKS) * blockDim.x + threadIdx.x;
        const size_t total4 = (size_t)Bn * MAP_CHn * GLOBAL_Mn * GLOBAL_Mn / 4;
        if (i4 >= total4) return;
        size_t f = i4 * 4;
        int gx = (int)(f % GLOBAL_Mn);
        size_t r = f / GLOBAL_Mn;
        int gy = (int)(r % GLOBAL_Mn);
        size_t bc = r / GLOBAL_Mn;
        int b = (int)(bc / MAP_CHn);
        int y1 = init_bounds[b * 4 + 0];
        int x1 = init_bounds[b * 4 + 2];
        if (gy >= y1 && gy < y1 + LOCAL_Mn && gx >= x1 && gx < x1 + LOCAL_Mn) return;
        vf4 v;
        if (anydone[b] != 0.0f) {
            v = (vf4)(0.0f);
        } else {
            v = __builtin_nontemporal_load((const vf4*)(init_gmap + f));
        }
        __builtin_nontemporal_store(v, (vf4*)(out_gmap + f));
        return;
    }

    // ---- update path ----
    int idx = blockIdx.x * blockDim.x + threadIdx.x;
    if (idx >= Bn * M2n) return;
    int b = idx / M2n, j = idx % M2n;
    int y = j / LOCAL_Mn, x = j % LOCAL_Mn;
    int y1 = init_bounds[b * 4 + 0];
    int x1 = init_bounds[b * 4 + 2];

    float lm[MAP_CHn], cr[MAP_CHn];
#pragma unroll
    for (int ch = 0; ch < MAP_CHn; ch++)
        lm[ch] = __builtin_nontemporal_load(init_lmap + ((size_t)(b * MAP_CHn + ch)) * M2n + j);
#pragma unroll
    for (int ch = 0; ch < MAP_CHn; ch++)
        cr[ch] = __builtin_nontemporal_load(
            init_gmap + ((size_t)(b * MAP_CHn + ch) * GLOBAL_Mn + (y1 + y)) * GLOBAL_Mn + (x1 + x));

    for (int t = 0; t < Tn; t++) {
        int done = done_flags[b * Tn + t];
        int upd  = upd_flags[b * Tn + t];
        if (done) {
#pragma unroll
            for (int ch = 0; ch < MAP_CHn; ch++) { lm[ch] = 0.0f; cr[ch] = 0.0f; }
        }
        float lx = ws_lpose[(t * Bn + b) * 3 + 0];
        float ly = ws_lpose[(t * Bn + b) * 3 + 1];
        float dxg = (float)x - lx / 5.0f;
        float dyg = (float)y - ly / 5.0f;
        float d2 = dxg * dxg + dyg * dyg;
        float agent = (d2 <= 4.0f) ? 1.0f : 0.0f;
        float close = (d2 <= 9.0f) ? 1.0f : 0.0f;

        int cell = (t * Bn + b) * M2n + j;
        uint2 rc = rec2[cell];                 // {counts, end-of-segment}
        unsigned n = rc.x & 0xFFFFu;
        lm[0] = fmaxf(lm[0], (rc.x >> 16) ? 1.0f : 0.0f);   // obst_n > 0
        lm[1] = fmaxf(lm[1], n ? 1.0f : 0.0f);              // n > 0
        lm[2] = agent;
        lm[3] = fmaxf(lm[3], close);

        if (n) {
            unsigned st = bsum[cell >> 10] + rc.y - n;      // segment start
            float sem[CATn];
#pragma unroll
            for (int c = 0; c < CATn; c++) sem[c] = 0.0f;
            const vf4* rp = (const vf4*)(recb + (size_t)st * CATn);
            for (unsigned k = 0; k < n; k++) {
                vf4 r0 = rp[0], r1 = rp[1], r2 = rp[2], r3 = rp[3];
                rp += 4;
                sem[0] += r0.x;  sem[1] += r0.y;  sem[2] += r0.z;  sem[3] += r0.w;
                sem[4] += r1.x;  sem[5] += r1.y;  sem[6] += r1.z;  sem[7] += r1.w;
                sem[8] += r2.x;  sem[9] += r2.y;  sem[10] += r2.z; sem[11] += r2.w;
                sem[12] += r3.x; sem[13] += r3.y; sem[14] += r3.z; sem[15] += r3.w;
            }
#pragma unroll
            for (int c = 0; c < CATn; c++)
                lm[NON_SEMn + c] = fmaxf(lm[NON_SEMn + c], fminf(fmaxf(sem[c], 0.0f), 1.0f));
        }
        if (upd) {
#pragma unroll
            for (int ch = 0; ch < MAP_CHn; ch++) cr[ch] = fmaxf(cr[ch], lm[ch]);
        }

        size_t fb = ((size_t)(b * Tn + t) * FEAT_CHn) * M2n + j;
#pragma unroll
        for (int ch = 0; ch < NON_SEMn; ch++)
            __builtin_nontemporal_store(lm[ch], out_feats + fb + (size_t)ch * M2n);
#pragma unroll
        for (int ch = 0; ch < NON_SEMn; ch++)
            __builtin_nontemporal_store(cr[ch], out_feats + fb + (size_t)(NON_SEMn + ch) * M2n);
#pragma unroll
        for (int c = 0; c < CATn; c++)
            __builtin_nontemporal_store(lm[NON_SEMn + c], out_feats + fb + (size_t)(2 * NON_SEMn + c) * M2n);
    }

#pragma unroll
    for (int ch = 0; ch < MAP_CHn; ch++)
        __builtin_nontemporal_store(lm[ch], out_lmap + ((size_t)(b * MAP_CHn + ch)) * M2n + j);
#pragma unroll
    for (int ch = 0; ch < MAP_CHn; ch++)
        __builtin_nontemporal_store(
            cr[ch], out_gmap + ((size_t)(b * MAP_CHn + ch) * GLOBAL_Mn + (y1 + y)) * GLOBAL_Mn + (x1 + x));
}

// ---------------- launch ----------------
extern "C" void kernel_launch(void* const* d_in, const int* in_sizes, int n_in,
                              void* d_out, int out_size, void* d_ws, size_t ws_size,
                              hipStream_t stream) {
    const float* obs        = (const float*)d_in[0];
    const float* pose_delta = (const float*)d_in[1];
    const int*   done_flags = (const int*)d_in[2];
    const int*   upd_flags  = (const int*)d_in[3];
    const float* cam_poses  = (const float*)d_in[4];
    const float* init_lmap  = (const float*)d_in[5];
    const float* init_gmap  = (const float*)d_in[6];
    const float* init_lpose = (const float*)d_in[7];
    const float* init_gpose = (const float*)d_in[8];
    const int*   init_bnds  = (const int*)d_in[9];
    const float* init_orgs  = (const float*)d_in[10];

    float* out = (float*)d_out;
    float* ws  = (float*)d_ws;

    float*    ws_lpose = ws + WS_LPOSE;
    float*    ws_anyd  = ws + WS_ANYD;
    uint2*    rec2     = (uint2*)(ws + WS_REC2);
    unsigned* bsum     = (unsigned*)(ws + WS_BSUM);
    int*      cellid   = (int*)(ws + WS_CELL);
    float*    recb     = ws + WS_RECB;

    float fx = (float)(160.0 / (2.0 * tan(79.0 * M_PI / 180.0 / 2.0)));

    pose_kernel<<<1, 64, 0, stream>>>(pose_delta, done_flags, upd_flags,
                                      init_lpose, init_gpose, init_bnds, init_orgs,
                                      ws_lpose, ws_anyd,
                                      out + OUT_LP, out + OUT_GP,
                                      out + OUT_BNDS, out + OUT_ORGS);

    (void)hipMemsetAsync(rec2, 0, (size_t)TBMn * sizeof(uint2), stream);

    project_kernel<<<(Pn + 255) / 256, 256, 0, stream>>>(
        obs, cam_poses, ws_lpose, rec2, cellid, fx);

    scan1_kernel<<<NBLK_SCAN, 256, 0, stream>>>(rec2, bsum);
    scan2_kernel<<<1, 256, 0, stream>>>(bsum);

    scatter_copy_kernel<<<(Pn + 255) / 256, 256, 0, stream>>>(
        obs, cellid, bsum, rec2, recb);

    mega_kernel<<<UPD_BLKS + GMAP_BLKS, 256, 0, stream>>>(
        rec2, bsum, recb, done_flags, upd_flags, ws_lpose,
        init_lmap, init_gmap, init_bnds, ws_anyd,
        out + OUT_FEATS, out + OUT_LMAP, out + OUT_GMAP);
}